// Round 1
// baseline (443.264 us; speedup 1.0000x reference)
//
#include <hip/hip_runtime.h>
#include <math.h>

#define B 2
#define C 128
#define DSZ 56
#define SL 3136      // 56*56
#define VOL 175616   // 56^3
#define S512 512
#define EPS 1e-5f

// workspace layout (float offsets)
#define OFF_POOL 0            // 3 * B*C*56 = 43008  (x_d, x_h, x_w)
#define OFF_GATE 43008        // 3 * 14336           (gd, gh, gw)
#define OFF_Y    86016        // B*C*512 = 131072
#define OFF_STAT 217088       // 4  (mu,rs per batch)
#define OFF_CA   217092       // B*C = 256
#define PCL 14336             // B*C*56

// ---------------- K1: axis pools ----------------
// one block per (b,c). 1024 threads; threads 0..783 own fixed (h, w4).
__global__ __launch_bounds__(1024) void k1_pool(const float* __restrict__ x,
                                                float* __restrict__ ws) {
    int c = blockIdx.x, b = blockIdx.y;
    int bc = b * C + c;
    const float4* base = (const float4*)(x + (size_t)bc * VOL);
    int t = threadIdx.x;
    __shared__ float s_red[56 * 16];
    __shared__ float s_h[56];
    __shared__ float s_w[56];
    if (t < 56) { s_h[t] = 0.f; s_w[t] = 0.f; }
    bool active = (t < 784);
    int h = t / 14, w4 = t % 14;
    int lane = t & 63, wave = t >> 6;
    float hacc = 0.f, wa0 = 0.f, wa1 = 0.f, wa2 = 0.f, wa3 = 0.f;
    float4 v = active ? base[t] : make_float4(0.f, 0.f, 0.f, 0.f);
    for (int d = 0; d < 56; ++d) {
        float4 vn = make_float4(0.f, 0.f, 0.f, 0.f);
        if (d < 55 && active) vn = base[(d + 1) * 784 + t];
        float s4 = v.x + v.y + v.z + v.w;
        hacc += s4; wa0 += v.x; wa1 += v.y; wa2 += v.z; wa3 += v.w;
        float red = s4;
        #pragma unroll
        for (int off = 1; off < 64; off <<= 1) red += __shfl_xor(red, off);
        if (lane == 0) s_red[d * 16 + wave] = red;
        v = vn;
    }
    __syncthreads();
    if (active) {
        atomicAdd(&s_h[h], hacc);
        atomicAdd(&s_w[w4 * 4 + 0], wa0);
        atomicAdd(&s_w[w4 * 4 + 1], wa1);
        atomicAdd(&s_w[w4 * 4 + 2], wa2);
        atomicAdd(&s_w[w4 * 4 + 3], wa3);
    }
    __syncthreads();
    if (t < 56) {
        float dsum = 0.f;
        #pragma unroll
        for (int wv = 0; wv < 16; ++wv) dsum += s_red[t * 16 + wv];
        const float inv = 1.0f / 3136.0f;
        ws[OFF_POOL + 0 * PCL + bc * 56 + t] = dsum * inv;
        ws[OFF_POOL + 1 * PCL + bc * 56 + t] = s_h[t] * inv;
        ws[OFF_POOL + 2 * PCL + bc * 56 + t] = s_w[t] * inv;
    }
}

// ---------------- K2: gates (conv + GN(4) + sigmoid) ----------------
// grid = 24: blockIdx.x = sg*8 + b*4 + g
__global__ __launch_bounds__(256) void k2_gate(
    const float* __restrict__ w0, const float* __restrict__ b0,
    const float* __restrict__ w1, const float* __restrict__ b1,
    const float* __restrict__ w2, const float* __restrict__ b2,
    const float* __restrict__ w3, const float* __restrict__ b3,
    const float* __restrict__ g0, const float* __restrict__ be0,
    const float* __restrict__ g1, const float* __restrict__ be1,
    const float* __restrict__ g2, const float* __restrict__ be2,
    float* __restrict__ ws) {
    int idx = blockIdx.x;
    int sg = idx >> 3, rem = idx & 7;
    int b = rem >> 2, g = rem & 3;
    const float* wconv[4] = {w0, w1, w2, w3};
    const float* bconv[4] = {b0, b1, b2, b3};
    const float* gam[3] = {g0, g1, g2};
    const float* bet[3] = {be0, be1, be2};
    const int ksz[4] = {3, 5, 7, 9};
    int kg = ksz[g];
    int half = kg >> 1;
    __shared__ float s_in[32 * 56];
    __shared__ float s_wt[32 * 9];
    __shared__ float s_b[32];
    __shared__ float s_redu[8];
    int t = threadIdx.x;
    const float* sp = ws + OFF_POOL + sg * PCL + (b * C + g * 32) * 56;
    for (int e = t; e < 1792; e += 256) s_in[e] = sp[e];
    for (int e = t; e < 32 * kg; e += 256) s_wt[e] = wconv[g][e];
    if (t < 32) s_b[t] = bconv[g][t];
    __syncthreads();
    float vals[7];
    float sum = 0.f, sq = 0.f;
    {
        int ii = 0;
        for (int e = t; e < 1792; e += 256, ++ii) {
            int cl = e / 56, l = e % 56;
            float acc = s_b[cl];
            for (int tt = 0; tt < kg; ++tt) {
                int ll = l + tt - half;
                if (ll >= 0 && ll < 56) acc += s_in[cl * 56 + ll] * s_wt[cl * kg + tt];
            }
            vals[ii] = acc;
            sum += acc; sq += acc * acc;
        }
    }
    #pragma unroll
    for (int off = 1; off < 64; off <<= 1) {
        sum += __shfl_xor(sum, off);
        sq += __shfl_xor(sq, off);
    }
    int lane = t & 63, wv = t >> 6;
    if (lane == 0) { s_redu[wv] = sum; s_redu[4 + wv] = sq; }
    __syncthreads();
    sum = s_redu[0] + s_redu[1] + s_redu[2] + s_redu[3];
    sq = s_redu[4] + s_redu[5] + s_redu[6] + s_redu[7];
    float mean = sum / 1792.0f;
    float var = sq / 1792.0f - mean * mean;
    float rs = rsqrtf(var + EPS);
    float* gp = ws + OFF_GATE + sg * PCL + (b * C + g * 32) * 56;
    const float* ga = gam[sg];
    const float* be = bet[sg];
    {
        int ii = 0;
        for (int e = t; e < 1792; e += 256, ++ii) {
            int cl = e / 56;
            int cch = g * 32 + cl;
            float xn = (vals[ii] - mean) * rs * ga[cch] + be[cch];
            gp[e] = 1.0f / (1.0f + expf(-xn));
        }
    }
}

// ---------------- K3: gated 7^3 avg-pool -> y ----------------
// grid (8, C, B); block 256. threads 0..63 own (hh,ww).
__global__ __launch_bounds__(256) void k3_pooly(const float* __restrict__ x,
                                                float* __restrict__ ws) {
    int dd = blockIdx.x, c = blockIdx.y, b = blockIdx.z;
    int bc = b * C + c;
    __shared__ float xs[SL];
    __shared__ float s_gh[56];
    __shared__ float s_gw[56];
    int t = threadIdx.x;
    const float* gp = ws + OFF_GATE;
    if (t < 56) s_gh[t] = gp[1 * PCL + bc * 56 + t];
    else if (t < 112) s_gw[t - 56] = gp[2 * PCL + bc * 56 + (t - 56)];
    float acc = 0.f;
    const float* xp = x + (size_t)bc * VOL + (size_t)dd * 7 * SL;
    int hh = (t & 63) >> 3, ww = t & 7;
    for (int dz = 0; dz < 7; ++dz) {
        __syncthreads();
        const float4* src = (const float4*)(xp + dz * SL);
        float4* dst = (float4*)xs;
        for (int e = t; e < 784; e += 256) dst[e] = src[e];
        __syncthreads();
        if (t < 64) {
            float part = 0.f;
            for (int r = 0; r < 7; ++r) {
                int h_ = hh * 7 + r;
                const float* row = &xs[h_ * 56 + ww * 7];
                float rsum = 0.f;
                #pragma unroll
                for (int q = 0; q < 7; ++q) rsum += row[q] * s_gw[ww * 7 + q];
                part += s_gh[h_] * rsum;
            }
            acc += part * gp[0 * PCL + bc * 56 + dd * 7 + dz];
        }
    }
    if (t < 64) ws[OFF_Y + bc * S512 + dd * 64 + t] = acc * (1.0f / 343.0f);
}

// ---------------- K4a: per-batch GN(1) stats over y ----------------
__global__ __launch_bounds__(256) void k4a_stats(float* __restrict__ ws) {
    int b = blockIdx.x;
    const float4* yp = (const float4*)(ws + OFF_Y + b * 65536);
    int t = threadIdx.x;
    float sum = 0.f, sq = 0.f;
    for (int e = t; e < 16384; e += 256) {
        float4 v = yp[e];
        sum += v.x + v.y + v.z + v.w;
        sq += v.x * v.x + v.y * v.y + v.z * v.z + v.w * v.w;
    }
    __shared__ float s_redu[8];
    #pragma unroll
    for (int off = 1; off < 64; off <<= 1) {
        sum += __shfl_xor(sum, off);
        sq += __shfl_xor(sq, off);
    }
    int lane = t & 63, wv = t >> 6;
    if (lane == 0) { s_redu[wv] = sum; s_redu[4 + wv] = sq; }
    __syncthreads();
    if (t == 0) {
        sum = s_redu[0] + s_redu[1] + s_redu[2] + s_redu[3];
        sq = s_redu[4] + s_redu[5] + s_redu[6] + s_redu[7];
        float mean = sum / 65536.0f;
        float var = sq / 65536.0f - mean * mean;
        ws[OFF_STAT + b * 2] = mean;
        ws[OFF_STAT + b * 2 + 1] = rsqrtf(var + EPS);
    }
}

// ---------------- K4b: per-(b,head) channel attention -> ca ----------------
__global__ __launch_bounds__(256) void k4b_attn(
    const float* __restrict__ gn, const float* __restrict__ btn,
    const float* __restrict__ wq, const float* __restrict__ wk,
    const float* __restrict__ wv, float* __restrict__ ws) {
    int blk = blockIdx.x;
    int b = blk >> 3, hd = blk & 7;
    __shared__ float yn[16 * 514];
    __shared__ float s_sc[256];
    __shared__ float s_ybar[16];
    int t = threadIdx.x;
    float mean = ws[OFF_STAT + b * 2];
    float rs = ws[OFF_STAT + b * 2 + 1];
    const float* yp = ws + OFF_Y + b * 65536 + hd * 16 * S512;
    for (int e = t; e < 8192; e += 256) {
        int i = e >> 9, s = e & 511;
        int cch = hd * 16 + i;
        yn[i * 514 + s] = (yp[e] - mean) * rs * gn[cch] + btn[cch];
    }
    __syncthreads();
    int i = t >> 4, j = t & 15;
    const float* ri = &yn[i * 514];
    const float* rj = &yn[j * 514];
    float g = 0.f;
    for (int s = 0; s < 512; ++s) g += ri[s] * rj[s];
    s_sc[t] = wq[hd * 16 + i] * wk[hd * 16 + j] * 0.25f * g;
    if (t < 16) {
        const float* r = &yn[t * 514];
        float sb = 0.f;
        for (int s = 0; s < 512; ++s) sb += r[s];
        s_ybar[t] = sb * (1.0f / 512.0f);
    }
    __syncthreads();
    if (t < 16) {
        float m = -1e30f;
        #pragma unroll
        for (int jj = 0; jj < 16; ++jj) m = fmaxf(m, s_sc[t * 16 + jj]);
        float den = 0.f, num = 0.f;
        #pragma unroll
        for (int jj = 0; jj < 16; ++jj) {
            float e = expf(s_sc[t * 16 + jj] - m);
            den += e;
            num += e * wv[hd * 16 + jj] * s_ybar[jj];
        }
        float o = num / den;
        ws[OFF_CA + b * C + hd * 16 + t] = 1.0f / (1.0f + expf(-o));
    }
}

// ---------------- K5: out = ca * gd*gh*gw * x ----------------
// grid (56, C, B); block 256
__global__ __launch_bounds__(256) void k5_out(const float* __restrict__ x,
                                              const float* __restrict__ ws,
                                              float* __restrict__ out) {
    int d = blockIdx.x, c = blockIdx.y, b = blockIdx.z;
    int bc = b * C + c;
    __shared__ float s_gh[56];
    __shared__ float s_gw[56];
    int t = threadIdx.x;
    const float* gp = ws + OFF_GATE;
    if (t < 56) s_gh[t] = gp[1 * PCL + bc * 56 + t];
    else if (t < 112) s_gw[t - 56] = gp[2 * PCL + bc * 56 + (t - 56)];
    __syncthreads();
    float f = ws[OFF_CA + bc] * gp[0 * PCL + bc * 56 + d];
    const float4* xp = (const float4*)(x + (size_t)bc * VOL + (size_t)d * SL);
    float4* op = (float4*)(out + (size_t)bc * VOL + (size_t)d * SL);
    for (int e = t; e < 784; e += 256) {
        float4 v = xp[e];
        int o = e * 4;
        int h_ = o / 56;
        int w0 = o % 56;
        float fh = f * s_gh[h_];
        v.x *= fh * s_gw[w0];
        v.y *= fh * s_gw[w0 + 1];
        v.z *= fh * s_gw[w0 + 2];
        v.w *= fh * s_gw[w0 + 3];
        op[e] = v;
    }
}

extern "C" void kernel_launch(void* const* d_in, const int* in_sizes, int n_in,
                              void* d_out, int out_size, void* d_ws, size_t ws_size,
                              hipStream_t stream) {
    const float* x = (const float*)d_in[0];
    float* ws = (float*)d_ws;
    float* out = (float*)d_out;

    k1_pool<<<dim3(C, B), 1024, 0, stream>>>(x, ws);
    k2_gate<<<24, 256, 0, stream>>>(
        (const float*)d_in[1], (const float*)d_in[2],
        (const float*)d_in[3], (const float*)d_in[4],
        (const float*)d_in[5], (const float*)d_in[6],
        (const float*)d_in[7], (const float*)d_in[8],
        (const float*)d_in[9], (const float*)d_in[10],
        (const float*)d_in[11], (const float*)d_in[12],
        (const float*)d_in[13], (const float*)d_in[14],
        ws);
    k3_pooly<<<dim3(8, C, B), 256, 0, stream>>>(x, ws);
    k4a_stats<<<2, 256, 0, stream>>>(ws);
    k4b_attn<<<16, 256, 0, stream>>>(
        (const float*)d_in[15], (const float*)d_in[16],
        (const float*)d_in[17], (const float*)d_in[18],
        (const float*)d_in[19], ws);
    k5_out<<<dim3(56, C, B), 256, 0, stream>>>(x, ws, out);
}